// Round 2
// baseline (2796.336 us; speedup 1.0000x reference)
//
#include <hip/hip_runtime.h>
#include <hip/hip_bf16.h>
#include <math.h>

typedef __bf16 bf16_t;
typedef __bf16 bf16x8 __attribute__((ext_vector_type(8)));
typedef __bf16 bf16x4 __attribute__((ext_vector_type(4)));
typedef float  f32x4  __attribute__((ext_vector_type(4)));

#define NB   16384
#define EDIM 1024
#define FFD  4096
#define NCD  32

__device__ __forceinline__ float gelu_exact(float x) {
    return 0.5f * x * (1.0f + erff(x * 0.70710678118654752f));
}

__device__ __forceinline__ void gload16(const bf16_t* g, bf16_t* l) {
    __builtin_amdgcn_global_load_lds(
        (__attribute__((address_space(1))) void*)(g),
        (__attribute__((address_space(3))) void*)(l),
        16, 0, 0);
}

// ---------------------------------------------------------------------------
// Generic bf16 GEMM: C[m,n] = sum_k A[m,k] * Bw[n,k]  (+bias[n]) (+epilogue)
// A: [M,K] bf16 row-major; Bw: [N,K] bf16 row-major (i.e. x @ W.T with W=[N,K])
// 128x128 tile, 4 waves (2x2), 4x4 fragments of mfma_f32_16x16x32_bf16, BK=32.
// ---------------------------------------------------------------------------
enum { EPI_PLAIN = 0, EPI_RESF32 = 1, EPI_GELU = 2, EPI_RESBF16 = 3 };

template<int EPI>
__global__ __launch_bounds__(256)
void gemm128(const bf16_t* __restrict__ A, const bf16_t* __restrict__ Bw,
             const float* __restrict__ bias, const void* __restrict__ resid,
             bf16_t* __restrict__ out, int ldo, int coloff,
             int M, int N, int K)
{
    __shared__ bf16_t sA[128 * 32];
    __shared__ bf16_t sB[128 * 32];

    const int tid  = threadIdx.x;
    const int lane = tid & 63;
    const int wave = tid >> 6;
    const long bm = (long)blockIdx.y * 128;
    const long bn = (long)blockIdx.x * 128;
    const int wr = (wave >> 1) * 64;   // wave row offset in tile
    const int wc = (wave & 1) * 64;    // wave col offset in tile

    // staging geometry: each wave fills 32 rows (2 issues x 16 rows) of each tile
    const int srow = lane >> 2;          // 0..15 row within 16-row chunk
    const int scol = (lane & 3) * 8;     // element col offset (0,8,16,24)
    const int r0   = wave * 32;

    const bf16_t* gA = A  + (bm + r0 + srow) * (long)K + scol;
    const bf16_t* gB = Bw + (bn + r0 + srow) * (long)K + scol;
    bf16_t* lA = sA + r0 * 32;
    bf16_t* lB = sB + r0 * 32;

    // fragment read geometry
    const int fr = lane & 15;
    const int fk = (lane >> 4) * 8;
    const bf16_t* rA = sA + (wr + fr) * 32 + fk;
    const bf16_t* rB = sB + (wc + fr) * 32 + fk;

    f32x4 acc[4][4] = {};

    for (int kt = 0; kt < K; kt += 32) {
        gload16(gA + kt,                lA);
        gload16(gA + kt + 16 * (long)K, lA + 16 * 32);
        gload16(gB + kt,                lB);
        gload16(gB + kt + 16 * (long)K, lB + 16 * 32);
        __syncthreads();   // drains vmcnt before barrier (compiler-emitted)

        bf16x8 av[4], bv[4];
        #pragma unroll
        for (int i = 0; i < 4; ++i) {
            av[i] = *(const bf16x8*)(rA + i * 16 * 32);
            bv[i] = *(const bf16x8*)(rB + i * 16 * 32);
        }
        #pragma unroll
        for (int mi = 0; mi < 4; ++mi)
            #pragma unroll
            for (int ni = 0; ni < 4; ++ni)
                acc[mi][ni] = __builtin_amdgcn_mfma_f32_16x16x32_bf16(
                                  av[mi], bv[ni], acc[mi][ni], 0, 0, 0);
        __syncthreads();
    }

    // C/D layout: col = lane&15, row = (lane>>4)*4 + reg   [m89/m91 verified]
    const int rq = (lane >> 4) * 4;
    #pragma unroll
    for (int mi = 0; mi < 4; ++mi) {
        #pragma unroll
        for (int ni = 0; ni < 4; ++ni) {
            const long n = bn + wc + ni * 16 + fr;
            const float bval = bias ? bias[n] : 0.0f;
            #pragma unroll
            for (int r = 0; r < 4; ++r) {
                const long m = bm + wr + mi * 16 + rq + r;
                float v = acc[mi][ni][r] + bval;
                if (EPI == EPI_RESF32)  v += ((const float*)resid)[m * (long)N + n];
                if (EPI == EPI_RESBF16) v += (float)((const bf16_t*)resid)[m * (long)N + n];
                if (EPI == EPI_GELU)    v = gelu_exact(v);
                out[m * (long)ldo + coloff + n] = (bf16_t)v;
            }
        }
    }
}

// ---------------------------------------------------------------------------
// LayerNorm over 1024 fp32 -> bf16
// ---------------------------------------------------------------------------
__global__ __launch_bounds__(256)
void ln_f32(const float* __restrict__ X, const float* __restrict__ g,
            const float* __restrict__ b, bf16_t* __restrict__ out)
{
    const long row = blockIdx.x;
    const int t = threadIdx.x;
    f32x4 x = ((const f32x4*)(X + row * EDIM))[t];
    float s = x[0] + x[1] + x[2] + x[3];
    float q = x[0]*x[0] + x[1]*x[1] + x[2]*x[2] + x[3]*x[3];
    #pragma unroll
    for (int off = 32; off; off >>= 1) { s += __shfl_xor(s, off); q += __shfl_xor(q, off); }
    __shared__ float red[8];
    if ((t & 63) == 0) { red[(t >> 6) * 2] = s; red[(t >> 6) * 2 + 1] = q; }
    __syncthreads();
    s = red[0] + red[2] + red[4] + red[6];
    q = red[1] + red[3] + red[5] + red[7];
    const float mean = s * (1.0f / EDIM);
    const float rs = rsqrtf(q * (1.0f / EDIM) - mean * mean + 1e-5f);
    f32x4 gg = ((const f32x4*)g)[t];
    f32x4 bb = ((const f32x4*)b)[t];
    bf16x4 o;
    #pragma unroll
    for (int j = 0; j < 4; ++j) o[j] = (bf16_t)((x[j] - mean) * rs * gg[j] + bb[j]);
    ((bf16x4*)(out + row * EDIM))[t] = o;
}

// LayerNorm over 2048 bf16 -> bf16 (safe in-place: each thread reads/writes its own 8)
__global__ __launch_bounds__(256)
void ln_cat(const bf16_t* __restrict__ X, const float* __restrict__ g,
            const float* __restrict__ b, bf16_t* __restrict__ out)
{
    const long row = blockIdx.x;
    const int t = threadIdx.x;
    bf16x8 xv = ((const bf16x8*)(X + row * 2048))[t];
    float xf[8];
    float s = 0.f, q = 0.f;
    #pragma unroll
    for (int j = 0; j < 8; ++j) { xf[j] = (float)xv[j]; s += xf[j]; q += xf[j] * xf[j]; }
    #pragma unroll
    for (int off = 32; off; off >>= 1) { s += __shfl_xor(s, off); q += __shfl_xor(q, off); }
    __shared__ float red[8];
    if ((t & 63) == 0) { red[(t >> 6) * 2] = s; red[(t >> 6) * 2 + 1] = q; }
    __syncthreads();
    s = red[0] + red[2] + red[4] + red[6];
    q = red[1] + red[3] + red[5] + red[7];
    const float mean = s * (1.0f / 2048);
    const float rs = rsqrtf(q * (1.0f / 2048) - mean * mean + 1e-5f);
    f32x4 g0 = ((const f32x4*)g)[2 * t], g1 = ((const f32x4*)g)[2 * t + 1];
    f32x4 b0 = ((const f32x4*)b)[2 * t], b1 = ((const f32x4*)b)[2 * t + 1];
    bf16x8 o;
    #pragma unroll
    for (int j = 0; j < 4; ++j) o[j]     = (bf16_t)((xf[j]     - mean) * rs * g0[j] + b0[j]);
    #pragma unroll
    for (int j = 0; j < 4; ++j) o[4 + j] = (bf16_t)((xf[4 + j] - mean) * rs * g1[j] + b1[j]);
    ((bf16x8*)(out + row * 2048))[t] = o;
}

// LayerNorm over 1024 bf16 then exact GELU -> bf16
__global__ __launch_bounds__(256)
void ln_gelu(const bf16_t* __restrict__ X, const float* __restrict__ g,
             const float* __restrict__ b, bf16_t* __restrict__ out)
{
    const long row = blockIdx.x;
    const int t = threadIdx.x;
    bf16x4 xv = ((const bf16x4*)(X + row * EDIM))[t];
    float xf[4];
    float s = 0.f, q = 0.f;
    #pragma unroll
    for (int j = 0; j < 4; ++j) { xf[j] = (float)xv[j]; s += xf[j]; q += xf[j] * xf[j]; }
    #pragma unroll
    for (int off = 32; off; off >>= 1) { s += __shfl_xor(s, off); q += __shfl_xor(q, off); }
    __shared__ float red[8];
    if ((t & 63) == 0) { red[(t >> 6) * 2] = s; red[(t >> 6) * 2 + 1] = q; }
    __syncthreads();
    s = red[0] + red[2] + red[4] + red[6];
    q = red[1] + red[3] + red[5] + red[7];
    const float mean = s * (1.0f / EDIM);
    const float rs = rsqrtf(q * (1.0f / EDIM) - mean * mean + 1e-5f);
    f32x4 gg = ((const f32x4*)g)[t];
    f32x4 bb = ((const f32x4*)b)[t];
    bf16x4 o;
    #pragma unroll
    for (int j = 0; j < 4; ++j)
        o[j] = (bf16_t)gelu_exact((xf[j] - mean) * rs * gg[j] + bb[j]);
    ((bf16x4*)(out + row * EDIM))[t] = o;
}

// fp32 -> bf16 elementwise (n4 = element count / 4)
__global__ void f2b(const float* __restrict__ in, bf16_t* __restrict__ out, long n4)
{
    long i = (long)blockIdx.x * blockDim.x + threadIdx.x;
    const long stride = (long)gridDim.x * blockDim.x;
    for (; i < n4; i += stride) {
        f32x4 v = ((const f32x4*)in)[i];
        bf16x4 o;
        #pragma unroll
        for (int j = 0; j < 4; ++j) o[j] = (bf16_t)v[j];
        ((bf16x4*)out)[i] = o;
    }
}

// transpose-convert: out[j][k] = (bf16) in[k][j], EDIM x EDIM
__global__ void tconv(const float* __restrict__ in, bf16_t* __restrict__ out)
{
    const long x = (long)blockIdx.x * 256 + threadIdx.x;
    const int k = (int)(x & (EDIM - 1));
    const int j = (int)(x >> 10);
    out[(long)j * EDIM + k] = (bf16_t)in[(long)k * EDIM + j];
}

// bc[i] = sum_k Wo[i][k]*bv[k] + bo[i]
__global__ __launch_bounds__(256)
void bcomb_k(const float* __restrict__ Wo, const float* __restrict__ bv,
             const float* __restrict__ bo, float* __restrict__ bc)
{
    const int i = blockIdx.x;
    const int t = threadIdx.x;
    f32x4 w = ((const f32x4*)(Wo + (long)i * EDIM))[t];
    f32x4 v = ((const f32x4*)bv)[t];
    float s = w[0]*v[0] + w[1]*v[1] + w[2]*v[2] + w[3]*v[3];
    #pragma unroll
    for (int off = 32; off; off >>= 1) s += __shfl_xor(s, off);
    __shared__ float red[4];
    if ((t & 63) == 0) red[t >> 6] = s;
    __syncthreads();
    if (t == 0) bc[i] = red[0] + red[1] + red[2] + red[3] + bo[i];
}

// final tiny GEMM: out[m, 0..31] = u[m,:] @ W2.T + b2 ; fp32 out
__global__ __launch_bounds__(256)
void final_gemm(const bf16_t* __restrict__ U, const bf16_t* __restrict__ W2,
                const float* __restrict__ b2, float* __restrict__ out)
{
    const int t = threadIdx.x;
    const long row = (long)blockIdx.x * 8 + (t >> 5);
    const int col = t & 31;
    const bf16_t* u = U + row * EDIM;
    const bf16_t* w = W2 + (long)col * EDIM;
    float acc = 0.f;
    for (int k = 0; k < EDIM; k += 8) {
        bf16x8 uv = *(const bf16x8*)(u + k);
        bf16x8 wv = *(const bf16x8*)(w + k);
        #pragma unroll
        for (int j = 0; j < 8; ++j) acc += (float)uv[j] * (float)wv[j];
    }
    out[row * NCD + col] = acc + b2[col];
}

extern "C" void kernel_launch(void* const* d_in, const int* in_sizes, int n_in,
                              void* d_out, int out_size, void* d_ws, size_t ws_size,
                              hipStream_t stream)
{
    const float* lc_cls   = (const float*)d_in[0];
    const float* tab_emb  = (const float*)d_in[1];
    const float* ln_lc_g  = (const float*)d_in[2];
    const float* ln_lc_b  = (const float*)d_in[3];
    const float* ln_tab_g = (const float*)d_in[4];
    const float* ln_tab_b = (const float*)d_in[5];
    const float* alc_Wv   = (const float*)d_in[8];
    const float* alc_bv   = (const float*)d_in[11];
    const float* alc_Wo   = (const float*)d_in[12];
    const float* alc_bo   = (const float*)d_in[13];
    const float* atab_Wv  = (const float*)d_in[16];
    const float* atab_bv  = (const float*)d_in[19];
    const float* atab_Wo  = (const float*)d_in[20];
    const float* atab_bo  = (const float*)d_in[21];
    const float* flc_W1   = (const float*)d_in[22];
    const float* flc_b1   = (const float*)d_in[23];
    const float* flc_W2   = (const float*)d_in[24];
    const float* flc_b2   = (const float*)d_in[25];
    const float* ftab_W1  = (const float*)d_in[26];
    const float* ftab_b1  = (const float*)d_in[27];
    const float* ftab_W2  = (const float*)d_in[28];
    const float* ftab_b2  = (const float*)d_in[29];
    const float* on_g     = (const float*)d_in[30];
    const float* on_b     = (const float*)d_in[31];
    const float* c_W1     = (const float*)d_in[32];
    const float* c_b1     = (const float*)d_in[33];
    const float* c_ln_g   = (const float*)d_in[34];
    const float* c_ln_b   = (const float*)d_in[35];
    const float* c_W2     = (const float*)d_in[36];
    const float* c_b2     = (const float*)d_in[37];

    char* ws = (char*)d_ws;
    size_t woff = 0;
    auto walloc = [&](size_t bytes) {
        void* p = ws + woff;
        woff += (bytes + 255) & ~(size_t)255;
        return p;
    };
    // ---- persistent bf16 weights (~38.2 MiB) ----
    bf16_t* Wc_lc  = (bf16_t*)walloc((size_t)EDIM * EDIM * 2);
    bf16_t* Wc_tab = (bf16_t*)walloc((size_t)EDIM * EDIM * 2);
    bf16_t* W1lc_b = (bf16_t*)walloc((size_t)FFD * EDIM * 2);
    bf16_t* W2lc_b = (bf16_t*)walloc((size_t)EDIM * FFD * 2);
    bf16_t* W1tab_b= (bf16_t*)walloc((size_t)FFD * EDIM * 2);
    bf16_t* W2tab_b= (bf16_t*)walloc((size_t)EDIM * FFD * 2);
    bf16_t* cW1_b  = (bf16_t*)walloc((size_t)EDIM * 2 * EDIM * 2);
    bf16_t* cW2_b  = (bf16_t*)walloc((size_t)NCD * EDIM * 2);
    float*  bc_lc  = (float*)walloc(EDIM * 4);
    float*  bc_tab = (float*)walloc(EDIM * 4);

    // ---- activation arena (everything after the weights) ----
    char* arena = ws + woff;
    const size_t arena_sz = (ws_size > woff) ? (ws_size - woff) : 0;

    // pick super-chunk SB (rows processed per pass); need 6*SB*2048 + HC*8192 bytes
    int SB = NB;
    while (SB > 128) {
        size_t S2 = (size_t)SB * 2048;
        size_t hsz = (size_t)((SB < 2048) ? SB : 2048) * 8192;
        if (6 * S2 + hsz <= arena_sz) break;
        SB >>= 1;
    }
    const int HC = (SB < 2048) ? SB : 2048;   // FFN hidden-chunk rows
    const size_t S2 = (size_t)SB * 2048;      // bytes of one [SB,1024] bf16 buffer
    bf16_t* lc_n  = (bf16_t*)(arena);
    bf16_t* tab_n = (bf16_t*)(arena + S2);
    bf16_t* lc_x  = (bf16_t*)(arena + 2 * S2);
    bf16_t* tab_x = (bf16_t*)(arena + 3 * S2);
    bf16_t* cat   = (bf16_t*)(arena + 4 * S2);   // [SB,2048]; LN'd in place
    bf16_t* hbuf  = (bf16_t*)(arena + 6 * S2);   // [HC,4096]
    bf16_t* tbuf  = lc_n;                        // dead by classifier stage
    bf16_t* ubuf  = tab_n;

    // ---- weight prep (once). Temps live in the arena (used before activations).
    bf16_t* Wo_lc_b  = (bf16_t*)(arena);                    // 2 MiB
    bf16_t* Wo_tab_b = (bf16_t*)(arena + (size_t)2  * 1024 * 1024);
    bf16_t* WvT_lc   = (bf16_t*)(arena + (size_t)4  * 1024 * 1024);
    bf16_t* WvT_tab  = (bf16_t*)(arena + (size_t)6  * 1024 * 1024);

    f2b<<<512, 256, 0, stream>>>(alc_Wo,  Wo_lc_b,  (long)EDIM * EDIM / 4);
    f2b<<<512, 256, 0, stream>>>(atab_Wo, Wo_tab_b, (long)EDIM * EDIM / 4);
    tconv<<<EDIM * EDIM / 256, 256, 0, stream>>>(alc_Wv,  WvT_lc);
    tconv<<<EDIM * EDIM / 256, 256, 0, stream>>>(atab_Wv, WvT_tab);
    f2b<<<2048, 256, 0, stream>>>(flc_W1,  W1lc_b,  (long)FFD * EDIM / 4);
    f2b<<<2048, 256, 0, stream>>>(flc_W2,  W2lc_b,  (long)EDIM * FFD / 4);
    f2b<<<2048, 256, 0, stream>>>(ftab_W1, W1tab_b, (long)FFD * EDIM / 4);
    f2b<<<2048, 256, 0, stream>>>(ftab_W2, W2tab_b, (long)EDIM * FFD / 4);
    f2b<<<1024, 256, 0, stream>>>(c_W1,    cW1_b,   (long)EDIM * 2 * EDIM / 4);
    f2b<<<32,   256, 0, stream>>>(c_W2,    cW2_b,   (long)NCD * EDIM / 4);
    bcomb_k<<<EDIM, 256, 0, stream>>>(alc_Wo,  alc_bv,  alc_bo,  bc_lc);
    bcomb_k<<<EDIM, 256, 0, stream>>>(atab_Wo, atab_bv, atab_bo, bc_tab);
    // Wcomb = Wo @ Wv  (softmax over a single key == 1, so attn collapses)
    gemm128<EPI_PLAIN><<<dim3(EDIM / 128, EDIM / 128), 256, 0, stream>>>(
        Wo_lc_b, WvT_lc, nullptr, nullptr, Wc_lc, EDIM, 0, EDIM, EDIM, EDIM);
    gemm128<EPI_PLAIN><<<dim3(EDIM / 128, EDIM / 128), 256, 0, stream>>>(
        Wo_tab_b, WvT_tab, nullptr, nullptr, Wc_tab, EDIM, 0, EDIM, EDIM, EDIM);

    // ---- batch loop over super-chunks of SB rows ----
    for (long c0 = 0; c0 < NB; c0 += SB) {
        const float* lcI  = lc_cls  + c0 * EDIM;
        const float* tabI = tab_emb + c0 * EDIM;

        ln_f32<<<SB, 256, 0, stream>>>(lcI,  ln_lc_g,  ln_lc_b,  lc_n);
        ln_f32<<<SB, 256, 0, stream>>>(tabI, ln_tab_g, ln_tab_b, tab_n);

        // cross = resid + x_n @ Wcomb.T + bcomb
        gemm128<EPI_RESF32><<<dim3(EDIM / 128, SB / 128), 256, 0, stream>>>(
            tab_n, Wc_lc, bc_lc, lcI, lc_x, EDIM, 0, SB, EDIM, EDIM);
        gemm128<EPI_RESF32><<<dim3(EDIM / 128, SB / 128), 256, 0, stream>>>(
            lc_n, Wc_tab, bc_tab, tabI, tab_x, EDIM, 0, SB, EDIM, EDIM);

        // FFNs (chunked over HC rows): h = gelu(x@W1.T+b1); out = x + h@W2.T+b2
        for (int r = 0; r < SB; r += HC) {
            gemm128<EPI_GELU><<<dim3(FFD / 128, HC / 128), 256, 0, stream>>>(
                lc_x + (size_t)r * EDIM, W1lc_b, flc_b1, nullptr, hbuf, FFD, 0, HC, FFD, EDIM);
            gemm128<EPI_RESBF16><<<dim3(EDIM / 128, HC / 128), 256, 0, stream>>>(
                hbuf, W2lc_b, flc_b2, lc_x + (size_t)r * EDIM,
                cat + (size_t)r * 2048, 2 * EDIM, 0, HC, EDIM, FFD);
        }
        for (int r = 0; r < SB; r += HC) {
            gemm128<EPI_GELU><<<dim3(FFD / 128, HC / 128), 256, 0, stream>>>(
                tab_x + (size_t)r * EDIM, W1tab_b, ftab_b1, nullptr, hbuf, FFD, 0, HC, FFD, EDIM);
            gemm128<EPI_RESBF16><<<dim3(EDIM / 128, HC / 128), 256, 0, stream>>>(
                hbuf, W2tab_b, ftab_b2, tab_x + (size_t)r * EDIM,
                cat + (size_t)r * 2048, 2 * EDIM, EDIM, HC, EDIM, FFD);
        }

        // output LN over 2048 (in place on cat)
        ln_cat<<<SB, 256, 0, stream>>>(cat, on_g, on_b, cat);

        // classifier head
        gemm128<EPI_PLAIN><<<dim3(EDIM / 128, SB / 128), 256, 0, stream>>>(
            cat, cW1_b, c_b1, nullptr, tbuf, EDIM, 0, SB, EDIM, 2 * EDIM);
        ln_gelu<<<SB, 256, 0, stream>>>(tbuf, c_ln_g, c_ln_b, ubuf);
        final_gemm<<<SB / 8, 256, 0, stream>>>(ubuf, cW2_b, c_b2,
                                               (float*)d_out + c0 * NCD);
    }
}

// Round 3
// 1415.766 us; speedup vs baseline: 1.9751x; 1.9751x over previous
//
#include <hip/hip_runtime.h>
#include <hip/hip_bf16.h>
#include <math.h>

typedef __bf16 bf16_t;
typedef __bf16 bf16x8 __attribute__((ext_vector_type(8)));
typedef __bf16 bf16x4 __attribute__((ext_vector_type(4)));
typedef float  f32x4  __attribute__((ext_vector_type(4)));

#define NB   16384
#define EDIM 1024
#define FFD  4096
#define NCD  32

__device__ __forceinline__ float gelu_exact(float x) {
    return 0.5f * x * (1.0f + erff(x * 0.70710678118654752f));
}

__device__ __forceinline__ void gload16(const bf16_t* g, bf16_t* l) {
    __builtin_amdgcn_global_load_lds(
        (__attribute__((address_space(1))) void*)(g),
        (__attribute__((address_space(3))) void*)(l),
        16, 0, 0);
}

// ---------------------------------------------------------------------------
// Dual-side bf16 GEMM: per blockIdx.z side s:
//   C_s[m,n] = sum_k A_s[m,k] * B_s[n,k]  (+bias_s[n]) (+epilogue)
// 128x128 tile, 4 waves (2x2), 4x4 frags of mfma_f32_16x16x32_bf16, BK=32.
// XCD-chunked bijective blockIdx swizzle (T1/m204) on the (x,y) grid.
// ---------------------------------------------------------------------------
enum { EPI_PLAIN = 0, EPI_RESF32 = 1, EPI_GELU = 2, EPI_RESBF16 = 3 };

struct GemmArgs {
    const bf16_t* A0; const bf16_t* A1;
    const bf16_t* B0; const bf16_t* B1;
    const float*  bias0; const float* bias1;
    const void*   res0; const void*  res1;
    bf16_t*       out0; bf16_t*      out1;
};

template<int EPI>
__global__ __launch_bounds__(256)
void gemm128(GemmArgs g, int ldo, int co0, int co1, int M, int N, int K)
{
    __shared__ bf16_t sA[128 * 32];
    __shared__ bf16_t sB[128 * 32];

    const int side = blockIdx.z;
    const bf16_t* __restrict__ A    = side ? g.A1   : g.A0;
    const bf16_t* __restrict__ Bw   = side ? g.B1   : g.B0;
    const float*  __restrict__ bias = side ? g.bias1: g.bias0;
    const void*   __restrict__ resid= side ? g.res1 : g.res0;
    bf16_t*       __restrict__ out  = side ? g.out1 : g.out0;
    const int coloff = side ? co1 : co0;

    // bijective XCD-chunked swizzle (m204): same-XCD blocks get contiguous tiles
    const int nx = gridDim.x;
    const int nwg = nx * gridDim.y;
    int lin = blockIdx.y * nx + blockIdx.x;
    {
        const int q = nwg >> 3, r = nwg & 7;
        const int xc = lin & 7, ix = lin >> 3;
        lin = (xc < r ? xc * (q + 1) : r * (q + 1) + (xc - r) * q) + ix;
    }
    const long bm = (long)(lin / nx) * 128;
    const long bn = (long)(lin % nx) * 128;

    const int tid  = threadIdx.x;
    const int lane = tid & 63;
    const int wave = tid >> 6;
    const int wr = (wave >> 1) * 64;
    const int wc = (wave & 1) * 64;

    const int srow = lane >> 2;
    const int scol = (lane & 3) * 8;
    const int r0   = wave * 32;

    const bf16_t* gA = A  + (bm + r0 + srow) * (long)K + scol;
    const bf16_t* gB = Bw + (bn + r0 + srow) * (long)K + scol;
    bf16_t* lA = sA + r0 * 32;
    bf16_t* lB = sB + r0 * 32;

    const int fr = lane & 15;
    const int fk = (lane >> 4) * 8;
    const bf16_t* rA = sA + (wr + fr) * 32 + fk;
    const bf16_t* rB = sB + (wc + fr) * 32 + fk;

    f32x4 acc[4][4] = {};

    for (int kt = 0; kt < K; kt += 32) {
        gload16(gA + kt,                lA);
        gload16(gA + kt + 16 * (long)K, lA + 16 * 32);
        gload16(gB + kt,                lB);
        gload16(gB + kt + 16 * (long)K, lB + 16 * 32);
        __syncthreads();

        bf16x8 av[4], bv[4];
        #pragma unroll
        for (int i = 0; i < 4; ++i) {
            av[i] = *(const bf16x8*)(rA + i * 16 * 32);
            bv[i] = *(const bf16x8*)(rB + i * 16 * 32);
        }
        #pragma unroll
        for (int mi = 0; mi < 4; ++mi)
            #pragma unroll
            for (int ni = 0; ni < 4; ++ni)
                acc[mi][ni] = __builtin_amdgcn_mfma_f32_16x16x32_bf16(
                                  av[mi], bv[ni], acc[mi][ni], 0, 0, 0);
        __syncthreads();
    }

    // C/D layout: col = lane&15, row = (lane>>4)*4 + reg
    const int rq = (lane >> 4) * 4;
    #pragma unroll
    for (int mi = 0; mi < 4; ++mi) {
        #pragma unroll
        for (int ni = 0; ni < 4; ++ni) {
            const long n = bn + wc + ni * 16 + fr;
            const float bval = bias ? bias[n] : 0.0f;
            #pragma unroll
            for (int r = 0; r < 4; ++r) {
                const long m = bm + wr + mi * 16 + rq + r;
                float v = acc[mi][ni][r] + bval;
                if (EPI == EPI_RESF32)  v += ((const float*)resid)[m * (long)N + n];
                if (EPI == EPI_RESBF16) v += (float)((const bf16_t*)resid)[m * (long)N + n];
                if (EPI == EPI_GELU)    v = gelu_exact(v);
                out[m * (long)ldo + coloff + n] = (bf16_t)v;
            }
        }
    }
}

// ---------------------------------------------------------------------------
// Final head GEMM with MFMA: out[m, 0..31] = U[m,:]@W2.T + b2, f32 out.
// Block = 128 rows, 4 waves (32 rows each); B tile 32x32 per k-step in LDS.
// ---------------------------------------------------------------------------
__global__ __launch_bounds__(256)
void final_mfma(const bf16_t* __restrict__ U, const bf16_t* __restrict__ W2,
                const float* __restrict__ b2, float* __restrict__ out)
{
    __shared__ bf16_t sA[128 * 32];
    __shared__ bf16_t sB[32 * 32];
    const int tid = threadIdx.x, lane = tid & 63, wave = tid >> 6;
    const long bm = (long)blockIdx.x * 128;
    const int srow = lane >> 2, scol = (lane & 3) * 8;

    const bf16_t* gA = U + (bm + wave * 32 + srow) * (long)EDIM + scol;
    bf16_t* lA = sA + wave * 32 * 32;
    const bf16_t* gB = W2 + ((long)wave * 16 + srow) * EDIM + scol;  // waves 0,1
    bf16_t* lB = sB + wave * 16 * 32;

    const int fr = lane & 15, fk = (lane >> 4) * 8;
    const bf16_t* rA = sA + (wave * 32 + fr) * 32 + fk;
    const bf16_t* rB = sB + fr * 32 + fk;

    f32x4 acc[2][2] = {};
    for (int kt = 0; kt < EDIM; kt += 32) {
        gload16(gA + kt,             lA);
        gload16(gA + kt + 16 * EDIM, lA + 16 * 32);
        if (wave < 2) gload16(gB + kt, lB);
        __syncthreads();
        bf16x8 av[2], bv[2];
        av[0] = *(const bf16x8*)(rA);
        av[1] = *(const bf16x8*)(rA + 16 * 32);
        bv[0] = *(const bf16x8*)(rB);
        bv[1] = *(const bf16x8*)(rB + 16 * 32);
        #pragma unroll
        for (int mi = 0; mi < 2; ++mi)
            #pragma unroll
            for (int ni = 0; ni < 2; ++ni)
                acc[mi][ni] = __builtin_amdgcn_mfma_f32_16x16x32_bf16(
                                  av[mi], bv[ni], acc[mi][ni], 0, 0, 0);
        __syncthreads();
    }
    const int rq = (lane >> 4) * 4;
    #pragma unroll
    for (int mi = 0; mi < 2; ++mi)
        #pragma unroll
        for (int ni = 0; ni < 2; ++ni) {
            const int n = ni * 16 + fr;
            const float bval = b2[n];
            #pragma unroll
            for (int r = 0; r < 4; ++r) {
                const long m = bm + wave * 32 + mi * 16 + rq + r;
                out[m * NCD + n] = acc[mi][ni][r] + bval;
            }
        }
}

// ---------------------------------------------------------------------------
// LayerNorms / elementwise helpers
// ---------------------------------------------------------------------------
__global__ __launch_bounds__(256)
void ln_f32(const float* __restrict__ X, const float* __restrict__ g,
            const float* __restrict__ b, bf16_t* __restrict__ out)
{
    const long row = blockIdx.x;
    const int t = threadIdx.x;
    f32x4 x = ((const f32x4*)(X + row * EDIM))[t];
    float s = x[0] + x[1] + x[2] + x[3];
    float q = x[0]*x[0] + x[1]*x[1] + x[2]*x[2] + x[3]*x[3];
    #pragma unroll
    for (int off = 32; off; off >>= 1) { s += __shfl_xor(s, off); q += __shfl_xor(q, off); }
    __shared__ float red[8];
    if ((t & 63) == 0) { red[(t >> 6) * 2] = s; red[(t >> 6) * 2 + 1] = q; }
    __syncthreads();
    s = red[0] + red[2] + red[4] + red[6];
    q = red[1] + red[3] + red[5] + red[7];
    const float mean = s * (1.0f / EDIM);
    const float rs = rsqrtf(q * (1.0f / EDIM) - mean * mean + 1e-5f);
    f32x4 gg = ((const f32x4*)g)[t];
    f32x4 bb = ((const f32x4*)b)[t];
    bf16x4 o;
    #pragma unroll
    for (int j = 0; j < 4; ++j) o[j] = (bf16_t)((x[j] - mean) * rs * gg[j] + bb[j]);
    ((bf16x4*)(out + row * EDIM))[t] = o;
}

__global__ __launch_bounds__(256)
void ln_cat(const bf16_t* __restrict__ X, const float* __restrict__ g,
            const float* __restrict__ b, bf16_t* __restrict__ out)
{
    const long row = blockIdx.x;
    const int t = threadIdx.x;
    bf16x8 xv = ((const bf16x8*)(X + row * 2048))[t];
    float xf[8];
    float s = 0.f, q = 0.f;
    #pragma unroll
    for (int j = 0; j < 8; ++j) { xf[j] = (float)xv[j]; s += xf[j]; q += xf[j] * xf[j]; }
    #pragma unroll
    for (int off = 32; off; off >>= 1) { s += __shfl_xor(s, off); q += __shfl_xor(q, off); }
    __shared__ float red[8];
    if ((t & 63) == 0) { red[(t >> 6) * 2] = s; red[(t >> 6) * 2 + 1] = q; }
    __syncthreads();
    s = red[0] + red[2] + red[4] + red[6];
    q = red[1] + red[3] + red[5] + red[7];
    const float mean = s * (1.0f / 2048);
    const float rs = rsqrtf(q * (1.0f / 2048) - mean * mean + 1e-5f);
    f32x4 g0 = ((const f32x4*)g)[2 * t], g1 = ((const f32x4*)g)[2 * t + 1];
    f32x4 b0 = ((const f32x4*)b)[2 * t], b1 = ((const f32x4*)b)[2 * t + 1];
    bf16x8 o;
    #pragma unroll
    for (int j = 0; j < 4; ++j) o[j]     = (bf16_t)((xf[j]     - mean) * rs * g0[j] + b0[j]);
    #pragma unroll
    for (int j = 0; j < 4; ++j) o[4 + j] = (bf16_t)((xf[4 + j] - mean) * rs * g1[j] + b1[j]);
    ((bf16x8*)(out + row * 2048))[t] = o;
}

__global__ __launch_bounds__(256)
void ln_gelu(const bf16_t* __restrict__ X, const float* __restrict__ g,
             const float* __restrict__ b, bf16_t* __restrict__ out)
{
    const long row = blockIdx.x;
    const int t = threadIdx.x;
    bf16x4 xv = ((const bf16x4*)(X + row * EDIM))[t];
    float xf[4];
    float s = 0.f, q = 0.f;
    #pragma unroll
    for (int j = 0; j < 4; ++j) { xf[j] = (float)xv[j]; s += xf[j]; q += xf[j] * xf[j]; }
    #pragma unroll
    for (int off = 32; off; off >>= 1) { s += __shfl_xor(s, off); q += __shfl_xor(q, off); }
    __shared__ float red[8];
    if ((t & 63) == 0) { red[(t >> 6) * 2] = s; red[(t >> 6) * 2 + 1] = q; }
    __syncthreads();
    s = red[0] + red[2] + red[4] + red[6];
    q = red[1] + red[3] + red[5] + red[7];
    const float mean = s * (1.0f / EDIM);
    const float rs = rsqrtf(q * (1.0f / EDIM) - mean * mean + 1e-5f);
    f32x4 gg = ((const f32x4*)g)[t];
    f32x4 bb = ((const f32x4*)b)[t];
    bf16x4 o;
    #pragma unroll
    for (int j = 0; j < 4; ++j)
        o[j] = (bf16_t)gelu_exact((xf[j] - mean) * rs * gg[j] + bb[j]);
    ((bf16x4*)(out + row * EDIM))[t] = o;
}

__global__ void f2b(const float* __restrict__ in, bf16_t* __restrict__ out, long n4)
{
    long i = (long)blockIdx.x * blockDim.x + threadIdx.x;
    const long stride = (long)gridDim.x * blockDim.x;
    for (; i < n4; i += stride) {
        f32x4 v = ((const f32x4*)in)[i];
        bf16x4 o;
        #pragma unroll
        for (int j = 0; j < 4; ++j) o[j] = (bf16_t)v[j];
        ((bf16x4*)out)[i] = o;
    }
}

__global__ void tconv(const float* __restrict__ in, bf16_t* __restrict__ out)
{
    const long x = (long)blockIdx.x * 256 + threadIdx.x;
    const int k = (int)(x & (EDIM - 1));
    const int j = (int)(x >> 10);
    out[(long)j * EDIM + k] = (bf16_t)in[(long)k * EDIM + j];
}

__global__ __launch_bounds__(256)
void bcomb_k(const float* __restrict__ Wo, const float* __restrict__ bv,
             const float* __restrict__ bo, float* __restrict__ bc)
{
    const int i = blockIdx.x;
    const int t = threadIdx.x;
    f32x4 w = ((const f32x4*)(Wo + (long)i * EDIM))[t];
    f32x4 v = ((const f32x4*)bv)[t];
    float s = w[0]*v[0] + w[1]*v[1] + w[2]*v[2] + w[3]*v[3];
    #pragma unroll
    for (int off = 32; off; off >>= 1) s += __shfl_xor(s, off);
    __shared__ float red[4];
    if ((t & 63) == 0) red[t >> 6] = s;
    __syncthreads();
    if (t == 0) bc[i] = red[0] + red[1] + red[2] + red[3] + bo[i];
}

extern "C" void kernel_launch(void* const* d_in, const int* in_sizes, int n_in,
                              void* d_out, int out_size, void* d_ws, size_t ws_size,
                              hipStream_t stream)
{
    const float* lc_cls   = (const float*)d_in[0];
    const float* tab_emb  = (const float*)d_in[1];
    const float* ln_lc_g  = (const float*)d_in[2];
    const float* ln_lc_b  = (const float*)d_in[3];
    const float* ln_tab_g = (const float*)d_in[4];
    const float* ln_tab_b = (const float*)d_in[5];
    const float* alc_Wv   = (const float*)d_in[8];
    const float* alc_bv   = (const float*)d_in[11];
    const float* alc_Wo   = (const float*)d_in[12];
    const float* alc_bo   = (const float*)d_in[13];
    const float* atab_Wv  = (const float*)d_in[16];
    const float* atab_bv  = (const float*)d_in[19];
    const float* atab_Wo  = (const float*)d_in[20];
    const float* atab_bo  = (const float*)d_in[21];
    const float* flc_W1   = (const float*)d_in[22];
    const float* flc_b1   = (const float*)d_in[23];
    const float* flc_W2   = (const float*)d_in[24];
    const float* flc_b2   = (const float*)d_in[25];
    const float* ftab_W1  = (const float*)d_in[26];
    const float* ftab_b1  = (const float*)d_in[27];
    const float* ftab_W2  = (const float*)d_in[28];
    const float* ftab_b2  = (const float*)d_in[29];
    const float* on_g     = (const float*)d_in[30];
    const float* on_b     = (const float*)d_in[31];
    const float* c_W1     = (const float*)d_in[32];
    const float* c_b1     = (const float*)d_in[33];
    const float* c_ln_g   = (const float*)d_in[34];
    const float* c_ln_b   = (const float*)d_in[35];
    const float* c_W2     = (const float*)d_in[36];
    const float* c_b2     = (const float*)d_in[37];

    char* ws = (char*)d_ws;
    size_t woff = 0;
    auto walloc = [&](size_t bytes) {
        void* p = ws + woff;
        woff += (bytes + 255) & ~(size_t)255;
        return p;
    };
    // persistent bf16 weights (~38.2 MiB)
    bf16_t* Wc_lc  = (bf16_t*)walloc((size_t)EDIM * EDIM * 2);
    bf16_t* Wc_tab = (bf16_t*)walloc((size_t)EDIM * EDIM * 2);
    bf16_t* W1lc_b = (bf16_t*)walloc((size_t)FFD * EDIM * 2);
    bf16_t* W2lc_b = (bf16_t*)walloc((size_t)EDIM * FFD * 2);
    bf16_t* W1tab_b= (bf16_t*)walloc((size_t)FFD * EDIM * 2);
    bf16_t* W2tab_b= (bf16_t*)walloc((size_t)EDIM * FFD * 2);
    bf16_t* cW1_b  = (bf16_t*)walloc((size_t)EDIM * 2 * EDIM * 2);
    bf16_t* cW2_b  = (bf16_t*)walloc((size_t)NCD * EDIM * 2);
    float*  bc_lc  = (float*)walloc(EDIM * 4);
    float*  bc_tab = (float*)walloc(EDIM * 4);

    char* arena = ws + woff;
    const size_t arena_sz = (ws_size > woff) ? (ws_size - woff) : 0;

    // Choose SB (rows per super-chunk) and HC (rows per FFN chunk).
    // Arena layout: lc_n|tab_n (cat aliases both) | lc_x | tab_x | hbuf0 | hbuf1
    // Need: 4*S2 + 2*HC*4096*2 bytes, S2 = SB*2048.
    int SB = NB, HC = 0;
    for (;;) {
        const size_t S2 = (size_t)SB * 2048;
        if (arena_sz > 4 * S2) {
            const size_t rem = arena_sz - 4 * S2;
            int hc = SB < 8192 ? SB : 8192;
            while (hc >= 128 && (size_t)hc * 16384 > rem) hc >>= 1;
            if (hc >= 128) { HC = hc; break; }
        }
        if (SB == 128) break;
        SB >>= 1;
    }
    if (!HC || arena_sz < (size_t)8 * 1024 * 1024) return;

    const size_t S2 = (size_t)SB * 2048;
    bf16_t* lc_n  = (bf16_t*)(arena);
    bf16_t* tab_n = (bf16_t*)(arena + S2);
    bf16_t* cat   = (bf16_t*)(arena);            // [SB,2048], aliases lc_n|tab_n
    bf16_t* lc_x  = (bf16_t*)(arena + 2 * S2);
    bf16_t* tab_x = (bf16_t*)(arena + 3 * S2);
    bf16_t* hbuf0 = (bf16_t*)(arena + 4 * S2);   // [HC,4096]
    bf16_t* hbuf1 = hbuf0 + (size_t)HC * FFD;
    bf16_t* tbuf  = lc_x;                        // dead by classifier stage
    bf16_t* ubuf  = tab_x;

    // weight-prep temps (transient, first 8 MiB of arena, used before activations)
    bf16_t* Wo_lc_b  = (bf16_t*)(arena);
    bf16_t* Wo_tab_b = (bf16_t*)(arena + (size_t)2 * 1024 * 1024);
    bf16_t* WvT_lc   = (bf16_t*)(arena + (size_t)4 * 1024 * 1024);
    bf16_t* WvT_tab  = (bf16_t*)(arena + (size_t)6 * 1024 * 1024);

    // ---- weight prep ----
    f2b<<<512, 256, 0, stream>>>(alc_Wo,  Wo_lc_b,  (long)EDIM * EDIM / 4);
    f2b<<<512, 256, 0, stream>>>(atab_Wo, Wo_tab_b, (long)EDIM * EDIM / 4);
    tconv<<<EDIM * EDIM / 256, 256, 0, stream>>>(alc_Wv,  WvT_lc);
    tconv<<<EDIM * EDIM / 256, 256, 0, stream>>>(atab_Wv, WvT_tab);
    f2b<<<2048, 256, 0, stream>>>(flc_W1,  W1lc_b,  (long)FFD * EDIM / 4);
    f2b<<<2048, 256, 0, stream>>>(flc_W2,  W2lc_b,  (long)EDIM * FFD / 4);
    f2b<<<2048, 256, 0, stream>>>(ftab_W1, W1tab_b, (long)FFD * EDIM / 4);
    f2b<<<2048, 256, 0, stream>>>(ftab_W2, W2tab_b, (long)EDIM * FFD / 4);
    f2b<<<1024, 256, 0, stream>>>(c_W1,    cW1_b,   (long)EDIM * 2 * EDIM / 4);
    f2b<<<32,   256, 0, stream>>>(c_W2,    cW2_b,   (long)NCD * EDIM / 4);
    bcomb_k<<<EDIM, 256, 0, stream>>>(alc_Wo,  alc_bv,  alc_bo,  bc_lc);
    bcomb_k<<<EDIM, 256, 0, stream>>>(atab_Wo, atab_bv, atab_bo, bc_tab);
    // Wcomb = Wo @ Wv (softmax over one key == 1), both sides in one launch
    {
        GemmArgs ga = { Wo_lc_b, Wo_tab_b, WvT_lc, WvT_tab,
                        nullptr, nullptr, nullptr, nullptr, Wc_lc, Wc_tab };
        gemm128<EPI_PLAIN><<<dim3(EDIM/128, EDIM/128, 2), 256, 0, stream>>>(
            ga, EDIM, 0, 0, EDIM, EDIM, EDIM);
    }

    // ---- batch loop ----
    for (long c0 = 0; c0 < NB; c0 += SB) {
        const float* lcI  = lc_cls  + c0 * EDIM;
        const float* tabI = tab_emb + c0 * EDIM;

        ln_f32<<<SB, 256, 0, stream>>>(lcI,  ln_lc_g,  ln_lc_b,  lc_n);
        ln_f32<<<SB, 256, 0, stream>>>(tabI, ln_tab_g, ln_tab_b, tab_n);

        // cross = resid + x_n @ Wcomb.T + bcomb  (both sides, one launch)
        {
            GemmArgs ga = { tab_n, lc_n, Wc_lc, Wc_tab, bc_lc, bc_tab,
                            lcI, tabI, lc_x, tab_x };
            gemm128<EPI_RESF32><<<dim3(EDIM/128, SB/128, 2), 256, 0, stream>>>(
                ga, EDIM, 0, 0, SB, EDIM, EDIM);
        }

        // FFNs: h = gelu(x@W1.T+b1); out = x + h@W2.T+b2 -> cat halves
        for (int r = 0; r < SB; r += HC) {
            {
                GemmArgs ga = { lc_x + (size_t)r * EDIM, tab_x + (size_t)r * EDIM,
                                W1lc_b, W1tab_b, flc_b1, ftab_b1,
                                nullptr, nullptr, hbuf0, hbuf1 };
                gemm128<EPI_GELU><<<dim3(FFD/128, HC/128, 2), 256, 0, stream>>>(
                    ga, FFD, 0, 0, HC, FFD, EDIM);
            }
            {
                GemmArgs ga = { hbuf0, hbuf1, W2lc_b, W2tab_b, flc_b2, ftab_b2,
                                lc_x + (size_t)r * EDIM, tab_x + (size_t)r * EDIM,
                                cat + (size_t)r * 2048, cat + (size_t)r * 2048 };
                gemm128<EPI_RESBF16><<<dim3(EDIM/128, HC/128, 2), 256, 0, stream>>>(
                    ga, 2 * EDIM, 0, EDIM, HC, EDIM, FFD);
            }
        }

        // output LN over 2048 (in place)
        ln_cat<<<SB, 256, 0, stream>>>(cat, on_g, on_b, cat);

        // classifier head
        {
            GemmArgs ga = { cat, cat, cW1_b, cW1_b, c_b1, c_b1,
                            nullptr, nullptr, tbuf, tbuf };
            gemm128<EPI_PLAIN><<<dim3(EDIM/128, SB/128, 1), 256, 0, stream>>>(
                ga, EDIM, 0, 0, SB, EDIM, 2 * EDIM);
        }
        ln_gelu<<<SB, 256, 0, stream>>>(tbuf, c_ln_g, c_ln_b, ubuf);
        final_mfma<<<SB / 128, 256, 0, stream>>>(ubuf, cW2_b, c_b2,
                                                 (float*)d_out + c0 * NCD);
    }
}

// Round 4
// 1144.444 us; speedup vs baseline: 2.4434x; 1.2371x over previous
//
#include <hip/hip_runtime.h>
#include <hip/hip_bf16.h>
#include <math.h>

typedef __bf16 bf16_t;
typedef __bf16 bf16x8 __attribute__((ext_vector_type(8)));
typedef __bf16 bf16x4 __attribute__((ext_vector_type(4)));
typedef float  f32x4  __attribute__((ext_vector_type(4)));

#define NB   16384
#define EDIM 1024
#define FFD  4096
#define NCD  32

__device__ __forceinline__ float gelu_exact(float x) {
    return 0.5f * x * (1.0f + erff(x * 0.70710678118654752f));
}

__device__ __forceinline__ void gload16(const bf16_t* g, bf16_t* l) {
    __builtin_amdgcn_global_load_lds(
        (__attribute__((address_space(1))) void*)(g),
        (__attribute__((address_space(3))) void*)(l),
        16, 0, 0);
}

enum { EPI_PLAIN = 0, EPI_RESF32 = 1, EPI_GELU = 2, EPI_RESBF16 = 3 };

struct GemmArgs {
    const bf16_t* A0; const bf16_t* A1;
    const bf16_t* B0; const bf16_t* B1;
    const float*  bias0; const float* bias1;
    const void*   res0; const void*  res1;
    bf16_t*       out0; bf16_t*      out1;
};

// ---------------------------------------------------------------------------
// gemm256: 256x256 tile, BK=32, 512 thr (8 waves 2Mx4N, wave tile 128x64).
// 4-deep LDS ring (128 KiB), global_load_lds staging, counted vmcnt(8) +
// one raw s_barrier per K-tile (T3/T4), XOR slot swizzle on both sides (T2),
// setprio around MFMA clusters (T5), bijective XCD swizzle (T1).
// C[m,n] = sum_k A[m,k]*B[n,k] (+bias) (+epilogue), dual-side via blockIdx.z.
// ---------------------------------------------------------------------------
template<int EPI>
__global__ __launch_bounds__(512, 2)
void gemm256(GemmArgs g, int ldo, int co0, int co1, int M, int N, int K)
{
    __shared__ bf16_t lds[65536];   // 4 bufs x (A 8192 + B 8192) elems

    const int side = blockIdx.z;
    const bf16_t* __restrict__ A    = side ? g.A1   : g.A0;
    const bf16_t* __restrict__ Bw   = side ? g.B1   : g.B0;
    const float*  __restrict__ bias = side ? g.bias1: g.bias0;
    const void*   __restrict__ resid= side ? g.res1 : g.res0;
    bf16_t*       __restrict__ out  = side ? g.out1 : g.out0;
    const int coloff = side ? co1 : co0;

    // T1: bijective XCD-chunked swizzle
    const int nx = gridDim.x;
    const int nwg = nx * gridDim.y;
    int lin = blockIdx.y * nx + blockIdx.x;
    {
        const int q = nwg >> 3, r = nwg & 7;
        const int xc = lin & 7, ix = lin >> 3;
        lin = (xc < r ? xc * (q + 1) : r * (q + 1) + (xc - r) * q) + ix;
    }
    const long bm = (long)(lin / nx) * 256;
    const long bn = (long)(lin % nx) * 256;

    const int tid = threadIdx.x, lane = tid & 63, wave = tid >> 6;
    const int wm = wave >> 2, wn = wave & 3;
    const int fr = lane & 15;
    // fragment read: k-slot group XOR'd by row (2-way residual conflict = free)
    const int sphys = ((lane >> 4) ^ (fr & 3) ^ ((fr >> 2) & 3)) * 8;
    const int abase = (wm * 128 + fr) * 32 + sphys;
    const int bbase = (wn * 64  + fr) * 32 + sphys;

    // staging: thread t covers row t>>2 (of a 128-row half), slot t&3;
    // global source column pre-swizzled with the same involution
    const int rowl = tid >> 2;
    const int scol = ((tid & 3) ^ (rowl & 3) ^ ((rowl >> 2) & 3)) * 8;
    const bf16_t* gA0 = A  + (bm + rowl)       * (long)K + scol;
    const bf16_t* gA1 = A  + (bm + 128 + rowl) * (long)K + scol;
    const bf16_t* gB0 = Bw + (bn + rowl)       * (long)K + scol;
    const bf16_t* gB1 = Bw + (bn + 128 + rowl) * (long)K + scol;
    bf16_t* const l0 = lds + wave * 512;       // wave-uniform LDS base

    const int nt = K >> 5;
    auto stage = [&](int ts, int bufi) {
        const long ko = (long)ts << 5;
        bf16_t* d = l0 + bufi * 16384;
        gload16(gA0 + ko, d);
        gload16(gA1 + ko, d + 4096);
        gload16(gB0 + ko, d + 8192);
        gload16(gB1 + ko, d + 12288);
    };
    stage(0, 0);
    stage(nt > 1 ? 1 : nt - 1, 1);
    stage(nt > 2 ? 2 : nt - 1, 2);

    f32x4 acc[8][4] = {};

    for (int t = 0; t < nt; ++t) {
        // wait own 4 oldest (tile t) done; barrier makes all waves' staging
        // visible and retires all reads of buf (t-1)&3 (safe to overwrite).
        asm volatile("s_waitcnt vmcnt(8)" ::: "memory");
        __builtin_amdgcn_s_barrier();
        asm volatile("" ::: "memory");   // pin LDS reads after the barrier

        int ts = t + 3; if (ts >= nt) ts = nt - 1;   // clamp: junk into dead buf
        stage(ts, (t + 3) & 3);

        const bf16_t* bA = lds + (t & 3) * 16384;
        const bf16_t* bB = bA + 8192;

        bf16x8 bfr[4], afr[4];
        #pragma unroll
        for (int ni = 0; ni < 4; ++ni) bfr[ni] = *(const bf16x8*)(bB + bbase + ni * 512);
        #pragma unroll
        for (int mi = 0; mi < 4; ++mi) afr[mi] = *(const bf16x8*)(bA + abase + mi * 512);
        __builtin_amdgcn_s_setprio(1);
        #pragma unroll
        for (int mi = 0; mi < 4; ++mi)
            #pragma unroll
            for (int ni = 0; ni < 4; ++ni)
                acc[mi][ni] = __builtin_amdgcn_mfma_f32_16x16x32_bf16(
                                  afr[mi], bfr[ni], acc[mi][ni], 0, 0, 0);
        __builtin_amdgcn_s_setprio(0);
        #pragma unroll
        for (int mi = 0; mi < 4; ++mi) afr[mi] = *(const bf16x8*)(bA + abase + 2048 + mi * 512);
        __builtin_amdgcn_s_setprio(1);
        #pragma unroll
        for (int mi = 0; mi < 4; ++mi)
            #pragma unroll
            for (int ni = 0; ni < 4; ++ni)
                acc[4 + mi][ni] = __builtin_amdgcn_mfma_f32_16x16x32_bf16(
                                  afr[mi], bfr[ni], acc[4 + mi][ni], 0, 0, 0);
        __builtin_amdgcn_s_setprio(0);
    }

    // epilogue: C/D layout col=lane&15, row=(lane>>4)*4+reg
    const int rq = (lane >> 4) * 4;
    #pragma unroll
    for (int mi = 0; mi < 8; ++mi) {
        #pragma unroll
        for (int ni = 0; ni < 4; ++ni) {
            const long n = bn + wn * 64 + ni * 16 + fr;
            const float bval = bias ? bias[n] : 0.0f;
            #pragma unroll
            for (int r = 0; r < 4; ++r) {
                const long m = bm + wm * 128 + mi * 16 + rq + r;
                float v = acc[mi][ni][r] + bval;
                if (EPI == EPI_RESF32)  v += ((const float*)resid)[m * (long)N + n];
                if (EPI == EPI_RESBF16) v += (float)((const bf16_t*)resid)[m * (long)N + n];
                if (EPI == EPI_GELU)    v = gelu_exact(v);
                out[m * (long)ldo + coloff + n] = (bf16_t)v;
            }
        }
    }
}

// ---------------------------------------------------------------------------
// gemm128 (proven): used for Wcomb prep and the classifier GEMM.
// ---------------------------------------------------------------------------
template<int EPI>
__global__ __launch_bounds__(256)
void gemm128(GemmArgs g, int ldo, int co0, int co1, int M, int N, int K)
{
    __shared__ bf16_t sA[128 * 32];
    __shared__ bf16_t sB[128 * 32];

    const int side = blockIdx.z;
    const bf16_t* __restrict__ A    = side ? g.A1   : g.A0;
    const bf16_t* __restrict__ Bw   = side ? g.B1   : g.B0;
    const float*  __restrict__ bias = side ? g.bias1: g.bias0;
    const void*   __restrict__ resid= side ? g.res1 : g.res0;
    bf16_t*       __restrict__ out  = side ? g.out1 : g.out0;
    const int coloff = side ? co1 : co0;

    const int nx = gridDim.x;
    const int nwg = nx * gridDim.y;
    int lin = blockIdx.y * nx + blockIdx.x;
    {
        const int q = nwg >> 3, r = nwg & 7;
        const int xc = lin & 7, ix = lin >> 3;
        lin = (xc < r ? xc * (q + 1) : r * (q + 1) + (xc - r) * q) + ix;
    }
    const long bm = (long)(lin / nx) * 128;
    const long bn = (long)(lin % nx) * 128;

    const int tid  = threadIdx.x;
    const int lane = tid & 63;
    const int wave = tid >> 6;
    const int wr = (wave >> 1) * 64;
    const int wc = (wave & 1) * 64;

    const int srow = lane >> 2;
    const int scol = (lane & 3) * 8;
    const int r0   = wave * 32;

    const bf16_t* gA = A  + (bm + r0 + srow) * (long)K + scol;
    const bf16_t* gB = Bw + (bn + r0 + srow) * (long)K + scol;
    bf16_t* lA = sA + r0 * 32;
    bf16_t* lB = sB + r0 * 32;

    const int fr = lane & 15;
    const int fk = (lane >> 4) * 8;
    const bf16_t* rA = sA + (wr + fr) * 32 + fk;
    const bf16_t* rB = sB + (wc + fr) * 32 + fk;

    f32x4 acc[4][4] = {};

    for (int kt = 0; kt < K; kt += 32) {
        gload16(gA + kt,                lA);
        gload16(gA + kt + 16 * (long)K, lA + 16 * 32);
        gload16(gB + kt,                lB);
        gload16(gB + kt + 16 * (long)K, lB + 16 * 32);
        __syncthreads();

        bf16x8 av[4], bv[4];
        #pragma unroll
        for (int i = 0; i < 4; ++i) {
            av[i] = *(const bf16x8*)(rA + i * 16 * 32);
            bv[i] = *(const bf16x8*)(rB + i * 16 * 32);
        }
        #pragma unroll
        for (int mi = 0; mi < 4; ++mi)
            #pragma unroll
            for (int ni = 0; ni < 4; ++ni)
                acc[mi][ni] = __builtin_amdgcn_mfma_f32_16x16x32_bf16(
                                  av[mi], bv[ni], acc[mi][ni], 0, 0, 0);
        __syncthreads();
    }

    const int rq = (lane >> 4) * 4;
    #pragma unroll
    for (int mi = 0; mi < 4; ++mi) {
        #pragma unroll
        for (int ni = 0; ni < 4; ++ni) {
            const long n = bn + wc + ni * 16 + fr;
            const float bval = bias ? bias[n] : 0.0f;
            #pragma unroll
            for (int r = 0; r < 4; ++r) {
                const long m = bm + wr + mi * 16 + rq + r;
                float v = acc[mi][ni][r] + bval;
                if (EPI == EPI_RESF32)  v += ((const float*)resid)[m * (long)N + n];
                if (EPI == EPI_RESBF16) v += (float)((const bf16_t*)resid)[m * (long)N + n];
                if (EPI == EPI_GELU)    v = gelu_exact(v);
                out[m * (long)ldo + coloff + n] = (bf16_t)v;
            }
        }
    }
}

// ---------------------------------------------------------------------------
// Final head GEMM with MFMA: out[m, 0..31] = U[m,:]@W2.T + b2, f32 out.
// ---------------------------------------------------------------------------
__global__ __launch_bounds__(256)
void final_mfma(const bf16_t* __restrict__ U, const bf16_t* __restrict__ W2,
                const float* __restrict__ b2, float* __restrict__ out)
{
    __shared__ bf16_t sA[128 * 32];
    __shared__ bf16_t sB[32 * 32];
    const int tid = threadIdx.x, lane = tid & 63, wave = tid >> 6;
    const long bm = (long)blockIdx.x * 128;
    const int srow = lane >> 2, scol = (lane & 3) * 8;

    const bf16_t* gA = U + (bm + wave * 32 + srow) * (long)EDIM + scol;
    bf16_t* lA = sA + wave * 32 * 32;
    const bf16_t* gB = W2 + ((long)wave * 16 + srow) * EDIM + scol;
    bf16_t* lB = sB + wave * 16 * 32;

    const int fr = lane & 15, fk = (lane >> 4) * 8;
    const bf16_t* rA = sA + (wave * 32 + fr) * 32 + fk;
    const bf16_t* rB = sB + fr * 32 + fk;

    f32x4 acc[2][2] = {};
    for (int kt = 0; kt < EDIM; kt += 32) {
        gload16(gA + kt,             lA);
        gload16(gA + kt + 16 * EDIM, lA + 16 * 32);
        if (wave < 2) gload16(gB + kt, lB);
        __syncthreads();
        bf16x8 av[2], bv[2];
        av[0] = *(const bf16x8*)(rA);
        av[1] = *(const bf16x8*)(rA + 16 * 32);
        bv[0] = *(const bf16x8*)(rB);
        bv[1] = *(const bf16x8*)(rB + 16 * 32);
        #pragma unroll
        for (int mi = 0; mi < 2; ++mi)
            #pragma unroll
            for (int ni = 0; ni < 2; ++ni)
                acc[mi][ni] = __builtin_amdgcn_mfma_f32_16x16x32_bf16(
                                  av[mi], bv[ni], acc[mi][ni], 0, 0, 0);
        __syncthreads();
    }
    const int rq = (lane >> 4) * 4;
    #pragma unroll
    for (int mi = 0; mi < 2; ++mi)
        #pragma unroll
        for (int ni = 0; ni < 2; ++ni) {
            const int n = ni * 16 + fr;
            const float bval = b2[n];
            #pragma unroll
            for (int r = 0; r < 4; ++r) {
                const long m = bm + wave * 32 + mi * 16 + rq + r;
                out[m * NCD + n] = acc[mi][ni][r] + bval;
            }
        }
}

// ---------------------------------------------------------------------------
// LayerNorms / elementwise helpers
// ---------------------------------------------------------------------------
__global__ __launch_bounds__(256)
void ln_f32(const float* __restrict__ X, const float* __restrict__ g,
            const float* __restrict__ b, bf16_t* __restrict__ out)
{
    const long row = blockIdx.x;
    const int t = threadIdx.x;
    f32x4 x = ((const f32x4*)(X + row * EDIM))[t];
    float s = x[0] + x[1] + x[2] + x[3];
    float q = x[0]*x[0] + x[1]*x[1] + x[2]*x[2] + x[3]*x[3];
    #pragma unroll
    for (int off = 32; off; off >>= 1) { s += __shfl_xor(s, off); q += __shfl_xor(q, off); }
    __shared__ float red[8];
    if ((t & 63) == 0) { red[(t >> 6) * 2] = s; red[(t >> 6) * 2 + 1] = q; }
    __syncthreads();
    s = red[0] + red[2] + red[4] + red[6];
    q = red[1] + red[3] + red[5] + red[7];
    const float mean = s * (1.0f / EDIM);
    const float rs = rsqrtf(q * (1.0f / EDIM) - mean * mean + 1e-5f);
    f32x4 gg = ((const f32x4*)g)[t];
    f32x4 bb = ((const f32x4*)b)[t];
    bf16x4 o;
    #pragma unroll
    for (int j = 0; j < 4; ++j) o[j] = (bf16_t)((x[j] - mean) * rs * gg[j] + bb[j]);
    ((bf16x4*)(out + row * EDIM))[t] = o;
}

__global__ __launch_bounds__(256)
void ln_cat(const bf16_t* __restrict__ X, const float* __restrict__ g,
            const float* __restrict__ b, bf16_t* __restrict__ out)
{
    const long row = blockIdx.x;
    const int t = threadIdx.x;
    bf16x8 xv = ((const bf16x8*)(X + row * 2048))[t];
    float xf[8];
    float s = 0.f, q = 0.f;
    #pragma unroll
    for (int j = 0; j < 8; ++j) { xf[j] = (float)xv[j]; s += xf[j]; q += xf[j] * xf[j]; }
    #pragma unroll
    for (int off = 32; off; off >>= 1) { s += __shfl_xor(s, off); q += __shfl_xor(q, off); }
    __shared__ float red[8];
    if ((t & 63) == 0) { red[(t >> 6) * 2] = s; red[(t >> 6) * 2 + 1] = q; }
    __syncthreads();
    s = red[0] + red[2] + red[4] + red[6];
    q = red[1] + red[3] + red[5] + red[7];
    const float mean = s * (1.0f / 2048);
    const float rs = rsqrtf(q * (1.0f / 2048) - mean * mean + 1e-5f);
    f32x4 g0 = ((const f32x4*)g)[2 * t], g1 = ((const f32x4*)g)[2 * t + 1];
    f32x4 b0 = ((const f32x4*)b)[2 * t], b1 = ((const f32x4*)b)[2 * t + 1];
    bf16x8 o;
    #pragma unroll
    for (int j = 0; j < 4; ++j) o[j]     = (bf16_t)((xf[j]     - mean) * rs * g0[j] + b0[j]);
    #pragma unroll
    for (int j = 0; j < 4; ++j) o[4 + j] = (bf16_t)((xf[4 + j] - mean) * rs * g1[j] + b1[j]);
    ((bf16x8*)(out + row * 2048))[t] = o;
}

__global__ __launch_bounds__(256)
void ln_gelu(const bf16_t* __restrict__ X, const float* __restrict__ g,
             const float* __restrict__ b, bf16_t* __restrict__ out)
{
    const long row = blockIdx.x;
    const int t = threadIdx.x;
    bf16x4 xv = ((const bf16x4*)(X + row * EDIM))[t];
    float xf[4];
    float s = 0.f, q = 0.f;
    #pragma unroll
    for (int j = 0; j < 4; ++j) { xf[j] = (float)xv[j]; s += xf[j]; q += xf[j] * xf[j]; }
    #pragma unroll
    for (int off = 32; off; off >>= 1) { s += __shfl_xor(s, off); q += __shfl_xor(q, off); }
    __shared__ float red[8];
    if ((t & 63) == 0) { red[(t >> 6) * 2] = s; red[(t >> 6) * 2 + 1] = q; }
    __syncthreads();
    s = red[0] + red[2] + red[4] + red[6];
    q = red[1] + red[3] + red[5] + red[7];
    const float mean = s * (1.0f / EDIM);
    const float rs = rsqrtf(q * (1.0f / EDIM) - mean * mean + 1e-5f);
    f32x4 gg = ((const f32x4*)g)[t];
    f32x4 bb = ((const f32x4*)b)[t];
    bf16x4 o;
    #pragma unroll
    for (int j = 0; j < 4; ++j)
        o[j] = (bf16_t)gelu_exact((xf[j] - mean) * rs * gg[j] + bb[j]);
    ((bf16x4*)(out + row * EDIM))[t] = o;
}

__global__ void f2b(const float* __restrict__ in, bf16_t* __restrict__ out, long n4)
{
    long i = (long)blockIdx.x * blockDim.x + threadIdx.x;
    const long stride = (long)gridDim.x * blockDim.x;
    for (; i < n4; i += stride) {
        f32x4 v = ((const f32x4*)in)[i];
        bf16x4 o;
        #pragma unroll
        for (int j = 0; j < 4; ++j) o[j] = (bf16_t)v[j];
        ((bf16x4*)out)[i] = o;
    }
}

__global__ void tconv(const float* __restrict__ in, bf16_t* __restrict__ out)
{
    const long x = (long)blockIdx.x * 256 + threadIdx.x;
    const int k = (int)(x & (EDIM - 1));
    const int j = (int)(x >> 10);
    out[(long)j * EDIM + k] = (bf16_t)in[(long)k * EDIM + j];
}

__global__ __launch_bounds__(256)
void bcomb_k(const float* __restrict__ Wo, const float* __restrict__ bv,
             const float* __restrict__ bo, float* __restrict__ bc)
{
    const int i = blockIdx.x;
    const int t = threadIdx.x;
    f32x4 w = ((const f32x4*)(Wo + (long)i * EDIM))[t];
    f32x4 v = ((const f32x4*)bv)[t];
    float s = w[0]*v[0] + w[1]*v[1] + w[2]*v[2] + w[3]*v[3];
    #pragma unroll
    for (int off = 32; off; off >>= 1) s += __shfl_xor(s, off);
    __shared__ float red[4];
    if ((t & 63) == 0) red[t >> 6] = s;
    __syncthreads();
    if (t == 0) bc[i] = red[0] + red[1] + red[2] + red[3] + bo[i];
}

extern "C" void kernel_launch(void* const* d_in, const int* in_sizes, int n_in,
                              void* d_out, int out_size, void* d_ws, size_t ws_size,
                              hipStream_t stream)
{
    const float* lc_cls   = (const float*)d_in[0];
    const float* tab_emb  = (const float*)d_in[1];
    const float* ln_lc_g  = (const float*)d_in[2];
    const float* ln_lc_b  = (const float*)d_in[3];
    const float* ln_tab_g = (const float*)d_in[4];
    const float* ln_tab_b = (const float*)d_in[5];
    const float* alc_Wv   = (const float*)d_in[8];
    const float* alc_bv   = (const float*)d_in[11];
    const float* alc_Wo   = (const float*)d_in[12];
    const float* alc_bo   = (const float*)d_in[13];
    const float* atab_Wv  = (const float*)d_in[16];
    const float* atab_bv  = (const float*)d_in[19];
    const float* atab_Wo  = (const float*)d_in[20];
    const float* atab_bo  = (const float*)d_in[21];
    const float* flc_W1   = (const float*)d_in[22];
    const float* flc_b1   = (const float*)d_in[23];
    const float* flc_W2   = (const float*)d_in[24];
    const float* flc_b2   = (const float*)d_in[25];
    const float* ftab_W1  = (const float*)d_in[26];
    const float* ftab_b1  = (const float*)d_in[27];
    const float* ftab_W2  = (const float*)d_in[28];
    const float* ftab_b2  = (const float*)d_in[29];
    const float* on_g     = (const float*)d_in[30];
    const float* on_b     = (const float*)d_in[31];
    const float* c_W1     = (const float*)d_in[32];
    const float* c_b1     = (const float*)d_in[33];
    const float* c_ln_g   = (const float*)d_in[34];
    const float* c_ln_b   = (const float*)d_in[35];
    const float* c_W2     = (const float*)d_in[36];
    const float* c_b2     = (const float*)d_in[37];

    char* ws = (char*)d_ws;
    size_t woff = 0;
    auto walloc = [&](size_t bytes) {
        void* p = ws + woff;
        woff += (bytes + 255) & ~(size_t)255;
        return p;
    };
    // persistent bf16 weights (~38.2 MiB)
    bf16_t* Wc_lc  = (bf16_t*)walloc((size_t)EDIM * EDIM * 2);
    bf16_t* Wc_tab = (bf16_t*)walloc((size_t)EDIM * EDIM * 2);
    bf16_t* W1lc_b = (bf16_t*)walloc((size_t)FFD * EDIM * 2);
    bf16_t* W2lc_b = (bf16_t*)walloc((size_t)EDIM * FFD * 2);
    bf16_t* W1tab_b= (bf16_t*)walloc((size_t)FFD * EDIM * 2);
    bf16_t* W2tab_b= (bf16_t*)walloc((size_t)EDIM * FFD * 2);
    bf16_t* cW1_b  = (bf16_t*)walloc((size_t)EDIM * 2 * EDIM * 2);
    bf16_t* cW2_b  = (bf16_t*)walloc((size_t)NCD * EDIM * 2);
    float*  bc_lc  = (float*)walloc(EDIM * 4);
    float*  bc_tab = (float*)walloc(EDIM * 4);

    char* arena = ws + woff;
    const size_t arena_sz = (ws_size > woff) ? (ws_size - woff) : 0;

    // SB rows per super-chunk; arena need = SB*24576 bytes:
    //   cat (SB*4096, aliases lc_n|tab_n) | lc_x | tab_x (SB*2048 each)
    //   hbuf0 | hbuf1 (SB*8192 each)
    int SB = NB;
    while (SB > 256 && (size_t)SB * 24576 > arena_sz) SB >>= 1;
    if ((size_t)SB * 24576 > arena_sz) return;

    const size_t S2 = (size_t)SB * 2048;
    bf16_t* lc_n  = (bf16_t*)(arena);
    bf16_t* tab_n = (bf16_t*)(arena + S2);
    bf16_t* cat   = (bf16_t*)(arena);
    bf16_t* lc_x  = (bf16_t*)(arena + 2 * S2);
    bf16_t* tab_x = (bf16_t*)(arena + 3 * S2);
    bf16_t* hbuf0 = (bf16_t*)(arena + 4 * S2);
    bf16_t* hbuf1 = (bf16_t*)(arena + 8 * S2);
    bf16_t* tbuf  = lc_x;
    bf16_t* ubuf  = tab_x;

    // weight-prep temps (first 8 MiB of arena; used before activations exist)
    bf16_t* Wo_lc_b  = (bf16_t*)(arena);
    bf16_t* Wo_tab_b = (bf16_t*)(arena + (size_t)2 * 1024 * 1024);
    bf16_t* WvT_lc   = (bf16_t*)(arena + (size_t)4 * 1024 * 1024);
    bf16_t* WvT_tab  = (bf16_t*)(arena + (size_t)6 * 1024 * 1024);

    // ---- weight prep ----
    f2b<<<512, 256, 0, stream>>>(alc_Wo,  Wo_lc_b,  (long)EDIM * EDIM / 4);
    f2b<<<512, 256, 0, stream>>>(atab_Wo, Wo_tab_b, (long)EDIM * EDIM / 4);
    tconv<<<EDIM * EDIM / 256, 256, 0, stream>>>(alc_Wv,  WvT_lc);
    tconv<<<EDIM * EDIM / 256, 256, 0, stream>>>(atab_Wv, WvT_tab);
    f2b<<<2048, 256, 0, stream>>>(flc_W1,  W1lc_b,  (long)FFD * EDIM / 4);
    f2b<<<2048, 256, 0, stream>>>(flc_W2,  W2lc_b,  (long)EDIM * FFD / 4);
    f2b<<<2048, 256, 0, stream>>>(ftab_W1, W1tab_b, (long)FFD * EDIM / 4);
    f2b<<<2048, 256, 0, stream>>>(ftab_W2, W2tab_b, (long)EDIM * FFD / 4);
    f2b<<<1024, 256, 0, stream>>>(c_W1,    cW1_b,   (long)EDIM * 2 * EDIM / 4);
    f2b<<<32,   256, 0, stream>>>(c_W2,    cW2_b,   (long)NCD * EDIM / 4);
    bcomb_k<<<EDIM, 256, 0, stream>>>(alc_Wo,  alc_bv,  alc_bo,  bc_lc);
    bcomb_k<<<EDIM, 256, 0, stream>>>(atab_Wo, atab_bv, atab_bo, bc_tab);
    {   // Wcomb = Wo @ Wv (softmax over a single key == 1)
        GemmArgs ga = { Wo_lc_b, Wo_tab_b, WvT_lc, WvT_tab,
                        nullptr, nullptr, nullptr, nullptr, Wc_lc, Wc_tab };
        gemm128<EPI_PLAIN><<<dim3(EDIM/128, EDIM/128, 2), 256, 0, stream>>>(
            ga, EDIM, 0, 0, EDIM, EDIM, EDIM);
    }

    // ---- batch loop ----
    for (long c0 = 0; c0 < NB; c0 += SB) {
        const float* lcI  = lc_cls  + c0 * EDIM;
        const float* tabI = tab_emb + c0 * EDIM;

        ln_f32<<<SB, 256, 0, stream>>>(lcI,  ln_lc_g,  ln_lc_b,  lc_n);
        ln_f32<<<SB, 256, 0, stream>>>(tabI, ln_tab_g, ln_tab_b, tab_n);

        {   // cross = resid + x_n @ Wcomb.T + bcomb
            GemmArgs ga = { tab_n, lc_n, Wc_lc, Wc_tab, bc_lc, bc_tab,
                            lcI, tabI, lc_x, tab_x };
            gemm256<EPI_RESF32><<<dim3(EDIM/256, SB/256, 2), 512, 0, stream>>>(
                ga, EDIM, 0, 0, SB, EDIM, EDIM);
        }
        {   // FFN1: h = gelu(x @ W1.T + b1)
            GemmArgs ga = { lc_x, tab_x, W1lc_b, W1tab_b, flc_b1, ftab_b1,
                            nullptr, nullptr, hbuf0, hbuf1 };
            gemm256<EPI_GELU><<<dim3(FFD/256, SB/256, 2), 512, 0, stream>>>(
                ga, FFD, 0, 0, SB, FFD, EDIM);
        }
        {   // FFN2: cat half = x + h @ W2.T + b2
            GemmArgs ga = { hbuf0, hbuf1, W2lc_b, W2tab_b, flc_b2, ftab_b2,
                            lc_x, tab_x, cat, cat };
            gemm256<EPI_RESBF16><<<dim3(EDIM/256, SB/256, 2), 512, 0, stream>>>(
                ga, 2 * EDIM, 0, EDIM, SB, EDIM, FFD);
        }

        // output LN over 2048 (in place)
        ln_cat<<<SB, 256, 0, stream>>>(cat, on_g, on_b, cat);

        {   // classifier GEMM (K=2048)
            GemmArgs ga = { cat, cat, cW1_b, cW1_b, c_b1, c_b1,
                            nullptr, nullptr, tbuf, tbuf };
            gemm128<EPI_PLAIN><<<dim3(EDIM/128, SB/128, 1), 256, 0, stream>>>(
                ga, EDIM, 0, 0, SB, EDIM, 2 * EDIM);
        }
        ln_gelu<<<SB, 256, 0, stream>>>(tbuf, c_ln_g, c_ln_b, ubuf);
        final_mfma<<<SB / 128, 256, 0, stream>>>(ubuf, cW2_b, c_b2,
                                                 (float*)d_out + c0 * NCD);
    }
}